// Round 16
// baseline (444.417 us; speedup 1.0000x reference)
//
#include <hip/hip_runtime.h>
#include <cstdint>
#include <cstddef>

#define E 1024
#define NB 32768
#define BM 128
#define BN 128

typedef __attribute__((ext_vector_type(4))) float f32x4;
typedef __attribute__((ext_vector_type(2))) float f32x2;
typedef __attribute__((ext_vector_type(8))) short bf16x8;
typedef long long i64;

__device__ __forceinline__ short f2bfs(float x) {
    __bf16 h = (__bf16)x;
    return __builtin_bit_cast(short, h);
}
__device__ __forceinline__ bf16x8 cvt8(f32x4 lo, f32x4 hi) {
    bf16x8 r;
#pragma unroll
    for (int j = 0; j < 4; ++j) { r[j] = f2bfs(lo[j]); r[j + 4] = f2bfs(hi[j]); }
    return r;
}
__device__ __forceinline__ unsigned char f2fp8(float x) {
    int r = __builtin_amdgcn_cvt_pk_fp8_f32(x, 0.f, 0, false);
    return (unsigned char)(r & 0xff);
}
// pack 2 f32 -> 2 fp8 e4m3 bytes
__device__ __forceinline__ short pack2fp8(f32x2 v) {
    int r = __builtin_amdgcn_cvt_pk_fp8_f32(v[0], v[1], 0, false);
    return (short)(r & 0xffff);
}

__device__ __forceinline__ void gload16(const void* g, void* l) {
    __builtin_amdgcn_global_load_lds(
        (__attribute__((address_space(1))) void*)g,
        (__attribute__((address_space(3))) void*)l, 16, 0, 0);
}

// ---------------- transpose f32 -> bf16 (Wv -> WvT) ----------------
__global__ __launch_bounds__(256) void wv_transpose(const float* W0, short* T0,
                                                    const float* W1, short* T1) {
    const float* W = blockIdx.z ? W1 : W0;
    short* T = blockIdx.z ? T1 : T0;
    __shared__ float tile[32][33];
    const int j0 = blockIdx.x * 32, i0 = blockIdx.y * 32;
    const int tx = threadIdx.x, ty = threadIdx.y; // (32,8)
#pragma unroll
    for (int r = 0; r < 4; ++r)
        tile[ty + 8 * r][tx] = W[(size_t)(i0 + ty + 8 * r) * E + j0 + tx];
    __syncthreads();
#pragma unroll
    for (int r = 0; r < 4; ++r)
        T[(size_t)(j0 + ty + 8 * r) * E + i0 + tx] = f2bfs(tile[tx][ty + 8 * r]);
}

// ---------------- c[n] = scale * (sum_i O[n][i]*bv[i] + ob[n]) ----------------
__global__ __launch_bounds__(256) void bias_fuse(const float* O0, const float* bv0, const float* ob0, const float* s0, float* c0,
                                                 const float* O1, const float* bv1, const float* ob1, const float* s1, float* c1) {
    const float* O  = blockIdx.z ? O1 : O0;
    const float* bv = blockIdx.z ? bv1 : bv0;
    const float* ob = blockIdx.z ? ob1 : ob0;
    const float* sc = blockIdx.z ? s1 : s0;
    float* c = blockIdx.z ? c1 : c0;
    const int n = blockIdx.x, t = threadIdx.x;
    float s = 0.f;
    for (int i = t; i < E; i += 256) s += O[(size_t)n * E + i] * bv[i];
#pragma unroll
    for (int o = 32; o; o >>= 1) s += __shfl_down(s, o);
    __shared__ float rs[4];
    if ((t & 63) == 0) rs[t >> 6] = s;
    __syncthreads();
    if (t == 0) c[n] = sc[0] * (rs[0] + rs[1] + rs[2] + rs[3] + ob[n]);
}

// ---------------- M-build GEMM (R3-proven): M = 64*(O @ WvT^T), fp8 out ----------------
struct GemmArgs {
    const char* A;      // f32, row stride arstride
    const short* B;     // bf16 [n][k]
    unsigned char* C;   // fp8 e4m3 [n][k], row stride 1024 B, value x64
};

__global__ __launch_bounds__(256, 3) void gemm_m(GemmArgs g0, GemmArgs g1,
                                                 int mb, int arstride) {
    const int nwg = gridDim.x;
    const int q = nwg >> 3;
    const int wgid = (blockIdx.x & 7) * q + (blockIdx.x >> 3);
    const int per = mb * 8;
    const int z = wgid / per;
    const int rem = wgid - z * per;
    const int bx = rem >> 3;
    const int by = rem & 7;
    GemmArgs ga = z ? g1 : g0;

    constexpr int ABYTES = 16384;
    __shared__ __align__(16) char lds[2][ABYTES + 8192];

    const int t = threadIdx.x;
    const int l = t & 63, w = t >> 6;
    const int am0 = bx * BM, bn0 = by * BN;

    const char* gA[4];
#pragma unroll
    for (int i = 0; i < 4; ++i) {
        int c = i * 4 + w;
        int row = c * 8 + (l >> 3);
        int slot = (l & 7) ^ (row & 7);
        gA[i] = ga.A + (size_t)(am0 + row) * arstride + slot * 16;
    }
    const short* gB[2];
#pragma unroll
    for (int i = 0; i < 2; ++i) {
        int c = i * 4 + w;
        int row = c * 16 + (l >> 2);
        int slot = (l & 3) ^ ((row >> 1) & 3);
        gB[i] = ga.B + (size_t)(bn0 + row) * E + slot * 8;
    }

    auto stage = [&](int buf, int kt) {
#pragma unroll
        for (int i = 0; i < 4; ++i)
            gload16(gA[i] + (size_t)kt * 4, &lds[buf][(i * 4 + w) * 1024]);
#pragma unroll
        for (int i = 0; i < 2; ++i)
            gload16(gB[i] + kt, &lds[buf][ABYTES + (i * 4 + w) * 1024]);
    };

    const int wm = w >> 1, wn = w & 1;
    const int r16 = l & 15, kg = l >> 4;
    int aoff[4][2], boff[4];
#pragma unroll
    for (int m = 0; m < 4; ++m) {
        int row = wm * 64 + m * 16 + r16;
        aoff[m][0] = row * 128 + ((kg * 2) ^ (row & 7)) * 16;
        aoff[m][1] = row * 128 + ((kg * 2 + 1) ^ (row & 7)) * 16;
    }
#pragma unroll
    for (int n = 0; n < 4; ++n) {
        int row = wn * 64 + n * 16 + r16;
        boff[n] = ABYTES + row * 64 + (kg ^ ((row >> 1) & 3)) * 16;
    }

    f32x4 acc[4][4] = {};

    auto compute = [&](int buf) {
        bf16x8 a[4], b[4];
#pragma unroll
        for (int m = 0; m < 4; ++m) {
            f32x4 lo = *(const f32x4*)&lds[buf][aoff[m][0]];
            f32x4 hi = *(const f32x4*)&lds[buf][aoff[m][1]];
            a[m] = cvt8(lo, hi);
        }
#pragma unroll
        for (int n = 0; n < 4; ++n)
            b[n] = *(const bf16x8*)&lds[buf][boff[n]];
#pragma unroll
        for (int m = 0; m < 4; ++m)
#pragma unroll
            for (int n = 0; n < 4; ++n)
                acc[m][n] = __builtin_amdgcn_mfma_f32_16x16x32_bf16(a[m], b[n], acc[m][n], 0, 0, 0);
    };

    stage(0, 0);
    __syncthreads();
#pragma unroll 1
    for (int kt = 0; kt < E; kt += 64) {
        stage(1, kt + 32);
        compute(0);
        __syncthreads();
        if (kt + 64 < E) stage(0, kt + 64);
        compute(1);
        __syncthreads();
    }

    const int ccol0 = bn0 + wn * 64 + r16;
    const int crow0 = am0 + wm * 64 + kg * 4;
#pragma unroll
    for (int m = 0; m < 4; ++m)
#pragma unroll
        for (int n = 0; n < 4; ++n)
#pragma unroll
            for (int qq = 0; qq < 4; ++qq) {
                int row = crow0 + m * 16 + qq;
                int col = ccol0 + n * 16;
                ga.C[(size_t)row * 1024 + col] = f2fp8(acc[m][n][qq] * 64.0f);
            }
}

// ============ fused: out = LN(q + (kv @ M^T)*alpha/64 + c) * g + b ============
// The untested 2x2 cell: 32-row tile / 2 blocks per CU (R14) + per-block K-phase
// rotation (R15). R14 failed at 430us because doubling the DMA request rate into
// the shared-slice hotspot amplified L2 contention; R15 removed the hotspot
// (310->289 at 1 block/CU). With rotation, co-resident blocks read DIFFERENT
// M-slices each phase, and one block's stage-drain + epilogue overlaps the
// other's MFMA (m114). acc[2][8]=64 VGPR + ~45 working fits the 128-reg cap of
// __launch_bounds__(512,4) (R14: CSV 64 VGPR, no spill). LDS 66.25KB.
struct FArgs {
    const float* kv;        // [32768][1024] f32  (GEMM A)
    const unsigned char* M; // [1024][1024] fp8 e4m3 [n][k], value x64, NO alpha
    const float* c;         // [1024] f32, alpha folded
    const float* q;         // [32768][1024] f32  (residual emb)
    const float* scale;     // alpha (1 elem)
    const float* g;
    const float* b;
    float* out;             // [32768][1024] f32
};

#define BBASE 2048

__global__ __launch_bounds__(512, 4) void fused_gemm_ln(FArgs f0, FArgs f1) {
    // pair-scheduling swizzle: consecutive slots on one XCD alternate tables at
    // the SAME mb, so the pair shares emb panels (kv of one = residual of other).
    const int bid = blockIdx.x;             // 0..2047
    const int u = bid >> 3, xcd = bid & 7;  // u 0..255
    const int z = u & 1;
    const int mb = xcd * 128 + (u >> 1);    // 0..1023
    const FArgs fa = z ? f1 : f0;
    const int r0 = mb * 32;
    const int off = u & 31;                 // K-phase rotation (L2 de-hotspot)

    __shared__ __align__(16) char lds[67840];

    const int t = threadIdx.x;
    const int l = t & 63, w = t >> 6;
    const int r16 = l & 15, kg = l >> 4;

    // ---- B staging map (R13-verbatim): 32KB/buf = 2048 16B-units;
    //      gi=c*512+t; row=gi>>1, s=gi&1; inverse swizzle s ^= (row>>2)&1 ----
    int bsrc[4];
#pragma unroll
    for (int c = 0; c < 4; ++c) {
        int gi = c * 512 + t;
        int row = gi >> 1, s = gi & 1;
        bsrc[c] = row * 1024 + ((s ^ ((row >> 2) & 1)) * 16);
    }
    auto stageB = [&](int buf, int kt) {   // kt = k index = byte offset in fp8 row
#pragma unroll
        for (int c = 0; c < 4; ++c)
            gload16(fa.M + bsrc[c] + kt,
                    &lds[BBASE + buf * 32768 + (c * 512 + t) * 16]);
    };

    // ---- A commit map: thread -> row t>>4 (32 rows), k-pair kp=t&15 (2 k each) ----
    const int ar = t >> 4, kp = t & 15;
    const float* Ag = fa.kv + (size_t)(r0 + ar) * E + kp * 2;
    const int awoff = ar * 32 + (((kp >> 2) ^ ((ar >> 2) & 3)) * 8) + (kp & 3) * 2;
    auto commitA = [&](int buf, f32x2 av) {
        *(short*)&lds[buf * 1024 + awoff] = pack2fp8(av);
    };

    // ---- read-side swizzled frag offsets ----
    int aoff[2], boff[8];
    const int kgh = kg >> 1, kglo = (kg & 1) * 8;
#pragma unroll
    for (int m = 0; m < 2; ++m) {
        int row = m * 16 + r16;
        aoff[m] = row * 32 + ((kg ^ ((row >> 2) & 3)) * 8);
    }
#pragma unroll
    for (int nf = 0; nf < 8; ++nf) {
        int row = w * 128 + nf * 16 + r16;
        boff[nf] = BBASE + row * 32 + ((kgh ^ ((row >> 2) & 1)) * 16) + kglo;
    }

    f32x4 acc[2][8] = {};

    auto compute = [&](int buf) {
        i64 a[2], b[8];
#pragma unroll
        for (int m = 0; m < 2; ++m)
            a[m] = *(const i64*)&lds[buf * 1024 + aoff[m]];
#pragma unroll
        for (int nf = 0; nf < 8; ++nf)
            b[nf] = *(const i64*)&lds[buf * 32768 + boff[nf]];
#pragma unroll
        for (int m = 0; m < 2; ++m)
#pragma unroll
            for (int nf = 0; nf < 8; ++nf)
                acc[m][nf] = __builtin_amdgcn_mfma_f32_16x16x32_fp8_fp8(a[m], b[nf], acc[m][nf], 0, 0, 0);
    };

    // rotated k for phase p
    auto K = [&](int p) { return ((p + off) & 31) << 5; };

    // ---- prologue (R13 pattern, rotated): buf0 staged with K(0); reg holds K(1) ----
    {
        f32x2 a0 = *(const f32x2*)(Ag + K(0));
        stageB(0, K(0));
        commitA(0, a0);
    }
    f32x2 a = *(const f32x2*)(Ag + K(1));
    __syncthreads();

#pragma unroll 1
    for (int p = 0; p < 32; p += 2) {
        const bool has2 = (p + 2) < 32;
        stageB(1, K(p + 1));
        compute(0);                           // B/A at K(p), buf0
        commitA(1, a);                        // A at K(p+1)
        if (has2) a = *(const f32x2*)(Ag + K(p + 2));
        __syncthreads();                      // buf1 staged+committed
        if (has2) stageB(0, K(p + 2));
        compute(1);                           // B/A at K(p+1), buf1
        if (has2) {
            commitA(0, a);                    // A at K(p+2)
            if (p + 3 < 32) a = *(const f32x2*)(Ag + K(p + 3));
        }
        __syncthreads();
    }
    __syncthreads();   // A region free for LN scratch

    // ---- epilogue: residual + LayerNorm ----
    float* S  = (float*)lds;             // [32][8] row sums   (A region)
    float* Qs = (float*)(lds + 1024);    // [32][8] row sumsq  (A region)
    float* CB = (float*)(lds + 67584);   // [32][2] mean,rstd

    const float sc = fa.scale[0] * (1.0f / 64.0f);
    const int colbase = w * 128 + r16;
    float cf[8];
#pragma unroll
    for (int nf = 0; nf < 8; ++nf) cf[nf] = fa.c[colbase + nf * 16];

    float sum_[2][4] = {}, sq_[2][4] = {};
#pragma unroll
    for (int m = 0; m < 2; ++m) {
#pragma unroll
        for (int nf = 0; nf < 8; ++nf) {
#pragma unroll
            for (int qq = 0; qq < 4; ++qq) {
                int lrow = m * 16 + kg * 4 + qq;
                float x = acc[m][nf][qq] * sc + cf[nf]
                        + fa.q[(size_t)(r0 + lrow) * E + colbase + nf * 16];
                acc[m][nf][qq] = x;
                sum_[m][qq] += x;
                sq_[m][qq] += x * x;
            }
        }
    }
#pragma unroll
    for (int m = 0; m < 2; ++m)
#pragma unroll
        for (int qq = 0; qq < 4; ++qq)
#pragma unroll
            for (int o = 1; o < 16; o <<= 1) {
                sum_[m][qq] += __shfl_xor(sum_[m][qq], o);
                sq_[m][qq] += __shfl_xor(sq_[m][qq], o);
            }
#pragma unroll
    for (int m = 0; m < 2; ++m)
#pragma unroll
        for (int qq = 0; qq < 4; ++qq)
            if (r16 == m * 4 + qq) {
                int lrow = m * 16 + kg * 4 + qq;
                S[lrow * 8 + w] = sum_[m][qq];
                Qs[lrow * 8 + w] = sq_[m][qq];
            }
    __syncthreads();
    if (t < 32) {
        float ss = 0.f, qs = 0.f;
#pragma unroll
        for (int i = 0; i < 8; ++i) { ss += S[t * 8 + i]; qs += Qs[t * 8 + i]; }
        float mean = ss * (1.0f / E);
        float var = qs * (1.0f / E) - mean * mean;
        CB[t * 2] = mean;
        CB[t * 2 + 1] = rsqrtf(var + 1e-5f);
    }
    __syncthreads();

    float gf[8], bf_[8];
#pragma unroll
    for (int nf = 0; nf < 8; ++nf) {
        gf[nf] = fa.g[colbase + nf * 16];
        bf_[nf] = fa.b[colbase + nf * 16];
    }
#pragma unroll
    for (int m = 0; m < 2; ++m)
#pragma unroll
        for (int qq = 0; qq < 4; ++qq) {
            int lrow = m * 16 + kg * 4 + qq;
            float mean = CB[lrow * 2], rstd = CB[lrow * 2 + 1];
            float* op = fa.out + (size_t)(r0 + lrow) * E + colbase;
#pragma unroll
            for (int nf = 0; nf < 8; ++nf)
                op[nf * 16] = (acc[m][nf][qq] - mean) * rstd * gf[nf] + bf_[nf];
        }
}

extern "C" void kernel_launch(void* const* d_in, const int* in_sizes, int n_in,
                              void* d_out, int out_size, void* d_ws, size_t ws_size,
                              hipStream_t stream) {
    const float* user_emb = (const float*)d_in[0];
    const float* item_emb = (const float*)d_in[1];
    const float* u2i_in_w = (const float*)d_in[2];
    const float* u2i_in_b = (const float*)d_in[3];
    const float* u2i_out_w = (const float*)d_in[4];
    const float* u2i_out_b = (const float*)d_in[5];
    const float* i2u_in_w = (const float*)d_in[6];
    const float* i2u_in_b = (const float*)d_in[7];
    const float* i2u_out_w = (const float*)d_in[8];
    const float* i2u_out_b = (const float*)d_in[9];
    const float* user_g = (const float*)d_in[10];
    const float* user_b = (const float*)d_in[11];
    const float* item_g = (const float*)d_in[12];
    const float* item_b = (const float*)d_in[13];
    const float* alpha = (const float*)d_in[14];
    const float* beta = (const float*)d_in[15];

    float* out_u = (float*)d_out;
    float* out_i = out_u + (size_t)NB * E;

    // workspace: WvT 2x2MB bf16, M 2x1MB fp8, c 2x4KB
    short* WvT1 = (short*)d_ws;
    short* WvT2 = WvT1 + (size_t)E * E;
    unsigned char* M1 = (unsigned char*)(WvT2 + (size_t)E * E);
    unsigned char* M2 = M1 + (size_t)E * E;
    float* c1 = (float*)(M2 + (size_t)E * E);
    float* c2 = c1 + E;

    const dim3 b256(256);

    // 1) WvT = transpose(in_w[2E:3E]) in bf16
    wv_transpose<<<dim3(32, 32, 2), dim3(32, 8), 0, stream>>>(
        u2i_in_w + 2 * (size_t)E * E, WvT1, i2u_in_w + 2 * (size_t)E * E, WvT2);

    // 2) c = scale * (O @ bv + ob)   (alpha/beta folded into c only)
    bias_fuse<<<dim3(E, 1, 2), b256, 0, stream>>>(
        u2i_out_w, u2i_in_b + 2 * E, u2i_out_b, alpha, c1,
        i2u_out_w, i2u_in_b + 2 * E, i2u_out_b, beta, c2);

    // 3) M = 64 * (O @ Wv)   fp8 e4m3 [n][k]  (x64 keeps M in e4m3 normal range)
    gemm_m<<<dim3(8 * 8 * 2), b256, 0, stream>>>(
        GemmArgs{(const char*)u2i_out_w, WvT1, M1},
        GemmArgs{(const char*)i2u_out_w, WvT2, M2},
        8, 4096);

    // 4) fused GEMM(fp8) + residual + LayerNorm: 2048 blocks x 512 thr, 2 blocks/CU
    fused_gemm_ln<<<dim3(2048), dim3(512), 0, stream>>>(
        FArgs{item_emb, M1, c1, user_emb, alpha, user_g, user_b, out_u},
        FArgs{user_emb, M2, c2, item_emb, beta, item_g, item_b, out_i});
}

// Round 17
// 366.178 us; speedup vs baseline: 1.2137x; 1.2137x over previous
//
#include <hip/hip_runtime.h>
#include <cstdint>
#include <cstddef>

#define E 1024
#define NB 32768
#define BM 128
#define BN 128

typedef __attribute__((ext_vector_type(4))) float f32x4;
typedef __attribute__((ext_vector_type(8))) short bf16x8;
typedef long long i64;

__device__ __forceinline__ short f2bfs(float x) {
    __bf16 h = (__bf16)x;
    return __builtin_bit_cast(short, h);
}
__device__ __forceinline__ bf16x8 cvt8(f32x4 lo, f32x4 hi) {
    bf16x8 r;
#pragma unroll
    for (int j = 0; j < 4; ++j) { r[j] = f2bfs(lo[j]); r[j + 4] = f2bfs(hi[j]); }
    return r;
}
// pack 4 f32 -> 4 fp8 e4m3 bytes (RNE)
__device__ __forceinline__ int pack4fp8(f32x4 v) {
    int r = __builtin_amdgcn_cvt_pk_fp8_f32(v[0], v[1], 0, false);
    r = __builtin_amdgcn_cvt_pk_fp8_f32(v[2], v[3], r, true);
    return r;
}
__device__ __forceinline__ unsigned char f2fp8(float x) {
    int r = __builtin_amdgcn_cvt_pk_fp8_f32(x, 0.f, 0, false);
    return (unsigned char)(r & 0xff);
}

__device__ __forceinline__ void gload16(const void* g, void* l) {
    __builtin_amdgcn_global_load_lds(
        (__attribute__((address_space(1))) void*)g,
        (__attribute__((address_space(3))) void*)l, 16, 0, 0);
}

// ---------------- transpose f32 -> bf16 (Wv -> WvT) ----------------
__global__ __launch_bounds__(256) void wv_transpose(const float* W0, short* T0,
                                                    const float* W1, short* T1) {
    const float* W = blockIdx.z ? W1 : W0;
    short* T = blockIdx.z ? T1 : T0;
    __shared__ float tile[32][33];
    const int j0 = blockIdx.x * 32, i0 = blockIdx.y * 32;
    const int tx = threadIdx.x, ty = threadIdx.y; // (32,8)
#pragma unroll
    for (int r = 0; r < 4; ++r)
        tile[ty + 8 * r][tx] = W[(size_t)(i0 + ty + 8 * r) * E + j0 + tx];
    __syncthreads();
#pragma unroll
    for (int r = 0; r < 4; ++r)
        T[(size_t)(j0 + ty + 8 * r) * E + i0 + tx] = f2bfs(tile[tx][ty + 8 * r]);
}

// ---------------- c[n] = scale * (sum_i O[n][i]*bv[i] + ob[n]) ----------------
__global__ __launch_bounds__(256) void bias_fuse(const float* O0, const float* bv0, const float* ob0, const float* s0, float* c0,
                                                 const float* O1, const float* bv1, const float* ob1, const float* s1, float* c1) {
    const float* O  = blockIdx.z ? O1 : O0;
    const float* bv = blockIdx.z ? bv1 : bv0;
    const float* ob = blockIdx.z ? ob1 : ob0;
    const float* sc = blockIdx.z ? s1 : s0;
    float* c = blockIdx.z ? c1 : c0;
    const int n = blockIdx.x, t = threadIdx.x;
    float s = 0.f;
    for (int i = t; i < E; i += 256) s += O[(size_t)n * E + i] * bv[i];
#pragma unroll
    for (int o = 32; o; o >>= 1) s += __shfl_down(s, o);
    __shared__ float rs[4];
    if ((t & 63) == 0) rs[t >> 6] = s;
    __syncthreads();
    if (t == 0) c[n] = sc[0] * (rs[0] + rs[1] + rs[2] + rs[3] + ob[n]);
}

// ---------------- M-build GEMM (R3-proven): M = 64*(O @ WvT^T), fp8 out ----------------
struct GemmArgs {
    const char* A;      // f32, row stride arstride
    const short* B;     // bf16 [n][k]
    unsigned char* C;   // fp8 e4m3 [n][k], row stride 1024 B, value x64
};

__global__ __launch_bounds__(256, 3) void gemm_m(GemmArgs g0, GemmArgs g1,
                                                 int mb, int arstride) {
    const int nwg = gridDim.x;
    const int q = nwg >> 3;
    const int wgid = (blockIdx.x & 7) * q + (blockIdx.x >> 3);
    const int per = mb * 8;
    const int z = wgid / per;
    const int rem = wgid - z * per;
    const int bx = rem >> 3;
    const int by = rem & 7;
    GemmArgs ga = z ? g1 : g0;

    constexpr int ABYTES = 16384;
    __shared__ __align__(16) char lds[2][ABYTES + 8192];

    const int t = threadIdx.x;
    const int l = t & 63, w = t >> 6;
    const int am0 = bx * BM, bn0 = by * BN;

    const char* gA[4];
#pragma unroll
    for (int i = 0; i < 4; ++i) {
        int c = i * 4 + w;
        int row = c * 8 + (l >> 3);
        int slot = (l & 7) ^ (row & 7);
        gA[i] = ga.A + (size_t)(am0 + row) * arstride + slot * 16;
    }
    const short* gB[2];
#pragma unroll
    for (int i = 0; i < 2; ++i) {
        int c = i * 4 + w;
        int row = c * 16 + (l >> 2);
        int slot = (l & 3) ^ ((row >> 1) & 3);
        gB[i] = ga.B + (size_t)(bn0 + row) * E + slot * 8;
    }

    auto stage = [&](int buf, int kt) {
#pragma unroll
        for (int i = 0; i < 4; ++i)
            gload16(gA[i] + (size_t)kt * 4, &lds[buf][(i * 4 + w) * 1024]);
#pragma unroll
        for (int i = 0; i < 2; ++i)
            gload16(gB[i] + kt, &lds[buf][ABYTES + (i * 4 + w) * 1024]);
    };

    const int wm = w >> 1, wn = w & 1;
    const int r16 = l & 15, kg = l >> 4;
    int aoff[4][2], boff[4];
#pragma unroll
    for (int m = 0; m < 4; ++m) {
        int row = wm * 64 + m * 16 + r16;
        aoff[m][0] = row * 128 + ((kg * 2) ^ (row & 7)) * 16;
        aoff[m][1] = row * 128 + ((kg * 2 + 1) ^ (row & 7)) * 16;
    }
#pragma unroll
    for (int n = 0; n < 4; ++n) {
        int row = wn * 64 + n * 16 + r16;
        boff[n] = ABYTES + row * 64 + (kg ^ ((row >> 1) & 3)) * 16;
    }

    f32x4 acc[4][4] = {};

    auto compute = [&](int buf) {
        bf16x8 a[4], b[4];
#pragma unroll
        for (int m = 0; m < 4; ++m) {
            f32x4 lo = *(const f32x4*)&lds[buf][aoff[m][0]];
            f32x4 hi = *(const f32x4*)&lds[buf][aoff[m][1]];
            a[m] = cvt8(lo, hi);
        }
#pragma unroll
        for (int n = 0; n < 4; ++n)
            b[n] = *(const bf16x8*)&lds[buf][boff[n]];
#pragma unroll
        for (int m = 0; m < 4; ++m)
#pragma unroll
            for (int n = 0; n < 4; ++n)
                acc[m][n] = __builtin_amdgcn_mfma_f32_16x16x32_bf16(a[m], b[n], acc[m][n], 0, 0, 0);
    };

    stage(0, 0);
    __syncthreads();
#pragma unroll 1
    for (int kt = 0; kt < E; kt += 64) {
        stage(1, kt + 32);
        compute(0);
        __syncthreads();
        if (kt + 64 < E) stage(0, kt + 64);
        compute(1);
        __syncthreads();
    }

    const int ccol0 = bn0 + wn * 64 + r16;
    const int crow0 = am0 + wm * 64 + kg * 4;
#pragma unroll
    for (int m = 0; m < 4; ++m)
#pragma unroll
        for (int n = 0; n < 4; ++n)
#pragma unroll
            for (int qq = 0; qq < 4; ++qq) {
                int row = crow0 + m * 16 + qq;
                int col = ccol0 + n * 16;
                ga.C[(size_t)row * 1024 + col] = f2fp8(acc[m][n][qq] * 64.0f);
            }
}

// ============ fused: out = LN(q + (kv @ M^T)*alpha/64 + c) * g + b ============
// R15 (best: 289us fused) with ONE change: BK=64 (16 phases instead of 32).
// At 1 block/CU the m132 occupancy tradeoff doesn't exist; halving barrier count
// amortizes the fixed per-phase costs (issue+drain+skew) over 2x the MFMAs.
// B rows now 64B (4x 16B slots) -> 2-bit bank hash (row>>1)&3 (generalizes the
// R13 conflict fix: over 16 consecutive rows each slot-xor value appears 4x ->
// uniform bank spread). LDS 136.5KB: A 2x4KB @0, B 2x64KB @8192. Rotation
// K(p)=((p+off)&15)*64, off=u&15, keeps co-running CUs on different M slices.
struct FArgs {
    const float* kv;        // [32768][1024] f32  (GEMM A)
    const unsigned char* M; // [1024][1024] fp8 e4m3 [n][k], value x64, NO alpha
    const float* c;         // [1024] f32, alpha folded
    const float* q;         // [32768][1024] f32  (residual emb)
    const float* scale;     // alpha (1 elem)
    const float* g;
    const float* b;
    float* out;             // [32768][1024] f32
};

#define BBASE 8192
struct A8 { f32x4 lo, hi; };

__global__ __launch_bounds__(512, 2) void fused_gemm_ln(FArgs f0, FArgs f1) {
    // pair-scheduling swizzle: consecutive slots on one XCD alternate tables at
    // the SAME mb, so the pair shares emb panels (kv of one = residual of other).
    const int bid = blockIdx.x;
    const int u = bid >> 3, xcd = bid & 7;
    const int z = u & 1;
    const int mb = xcd * 64 + (u >> 1);
    const FArgs fa = z ? f1 : f0;
    const int r0 = mb * 64;
    const int off = u & 15;                 // K-phase rotation (L2 de-hotspot)

    __shared__ __align__(16) char lds[139264];

    const int t = threadIdx.x;
    const int l = t & 63, w = t >> 6;
    const int r16 = l & 15, kg = l >> 4;

    // ---- B staging map: 64KB/buf = 4096 16B-units; gi=c*512+t; row=gi>>2,
    //      slot=gi&3; inverse swizzle on source: slot ^= (row>>1)&3 ----
    int bsrc[8];
#pragma unroll
    for (int c = 0; c < 8; ++c) {
        int gi = c * 512 + t;
        int row = gi >> 2, slot = gi & 3;
        bsrc[c] = row * 1024 + ((slot ^ ((row >> 1) & 3)) * 16);
    }
    auto stageB = [&](int buf, int kt) {   // kt = k index = byte offset in fp8 row
#pragma unroll
        for (int c = 0; c < 8; ++c)
            gload16(fa.M + bsrc[c] + kt,
                    &lds[BBASE + buf * 65536 + (c * 512 + t) * 16]);
    };

    // ---- A commit map: thread -> row t>>3 (64 rows), 8B half kp=t&7 (8 k) ----
    const int ar = t >> 3, kp = t & 7;
    const float* Ag = fa.kv + (size_t)(r0 + ar) * E + kp * 8;
    const int awoff = ar * 64 + (((kp >> 1) ^ ((ar >> 1) & 3)) * 16) + (kp & 1) * 8;
    auto loadA8 = [&](int kt) {
        A8 v;
        v.lo = *(const f32x4*)(Ag + kt);
        v.hi = *(const f32x4*)(Ag + kt + 4);
        return v;
    };
    auto commitA = [&](int buf, A8 v) {
        int p0 = pack4fp8(v.lo), p1 = pack4fp8(v.hi);
        i64 pk = ((i64)(unsigned)p0) | (((i64)p1) << 32);
        *(i64*)&lds[buf * 4096 + awoff] = pk;
    };

    // ---- read-side swizzled frag offsets (8B frags; slice s in {0,1}) ----
    int aoff[4][2], boff[8][2];
    const int kgh = kg >> 1, kglo = (kg & 1) * 8;
#pragma unroll
    for (int m = 0; m < 4; ++m) {
        int row = m * 16 + r16;
#pragma unroll
        for (int s = 0; s < 2; ++s)
            aoff[m][s] = row * 64 + (((s * 2 + kgh) ^ ((row >> 1) & 3)) * 16) + kglo;
    }
#pragma unroll
    for (int nf = 0; nf < 8; ++nf) {
        int row = w * 128 + nf * 16 + r16;
#pragma unroll
        for (int s = 0; s < 2; ++s)
            boff[nf][s] = BBASE + row * 64 + (((s * 2 + kgh) ^ ((row >> 1) & 3)) * 16) + kglo;
    }

    f32x4 acc[4][8] = {};

    auto compute = [&](int buf) {
#pragma unroll
        for (int s = 0; s < 2; ++s) {
            i64 a[4], b[8];
#pragma unroll
            for (int m = 0; m < 4; ++m)
                a[m] = *(const i64*)&lds[buf * 4096 + aoff[m][s]];
#pragma unroll
            for (int nf = 0; nf < 8; ++nf)
                b[nf] = *(const i64*)&lds[buf * 65536 + boff[nf][s]];
#pragma unroll
            for (int m = 0; m < 4; ++m)
#pragma unroll
                for (int nf = 0; nf < 8; ++nf)
                    acc[m][nf] = __builtin_amdgcn_mfma_f32_16x16x32_fp8_fp8(a[m], b[nf], acc[m][nf], 0, 0, 0);
        }
    };

    // rotated k for phase p (16 phases x 64 k)
    auto K = [&](int p) { return ((p + off) & 15) << 6; };

    // ---- prologue (R15 pattern): buf0 staged with K(0); reg holds K(1) ----
    {
        A8 a0 = loadA8(K(0));
        stageB(0, K(0));
        commitA(0, a0);
    }
    A8 a = loadA8(K(1));
    __syncthreads();

#pragma unroll 1
    for (int p = 0; p < 16; p += 2) {
        const bool has2 = (p + 2) < 16;
        stageB(1, K(p + 1));
        compute(0);                           // B/A at K(p), buf0
        commitA(1, a);                        // A at K(p+1)
        if (has2) a = loadA8(K(p + 2));
        __syncthreads();                      // buf1 staged+committed
        if (has2) stageB(0, K(p + 2));
        compute(1);                           // B/A at K(p+1), buf1
        if (has2) {
            commitA(0, a);                    // A at K(p+2)
            if (p + 3 < 16) a = loadA8(K(p + 3));
        }
        __syncthreads();
    }
    __syncthreads();   // A region free for LN scratch

    // ---- epilogue: residual + LayerNorm (R15-verbatim) ----
    float* S  = (float*)lds;            // [64][8] row sums   (A region)
    float* Qs = (float*)(lds + 2048);   // [64][8] row sumsq  (A region)
    float* CB = (float*)(lds + 4096);   // [64][2] mean,rstd  (A region)

    const float sc = fa.scale[0] * (1.0f / 64.0f);
    const int colbase = w * 128 + r16;
    float cf[8];
#pragma unroll
    for (int nf = 0; nf < 8; ++nf) cf[nf] = fa.c[colbase + nf * 16];

    float sum_[4][4] = {}, sq_[4][4] = {};
#pragma unroll
    for (int m = 0; m < 4; ++m) {
#pragma unroll
        for (int nf = 0; nf < 8; ++nf) {
#pragma unroll
            for (int qq = 0; qq < 4; ++qq) {
                int lrow = m * 16 + kg * 4 + qq;
                float x = acc[m][nf][qq] * sc + cf[nf]
                        + fa.q[(size_t)(r0 + lrow) * E + colbase + nf * 16];
                acc[m][nf][qq] = x;
                sum_[m][qq] += x;
                sq_[m][qq] += x * x;
            }
        }
    }
#pragma unroll
    for (int m = 0; m < 4; ++m)
#pragma unroll
        for (int qq = 0; qq < 4; ++qq)
#pragma unroll
            for (int o = 1; o < 16; o <<= 1) {
                sum_[m][qq] += __shfl_xor(sum_[m][qq], o);
                sq_[m][qq] += __shfl_xor(sq_[m][qq], o);
            }
#pragma unroll
    for (int m = 0; m < 4; ++m)
#pragma unroll
        for (int qq = 0; qq < 4; ++qq)
            if (r16 == m * 4 + qq) {
                int lrow = m * 16 + kg * 4 + qq;
                S[lrow * 8 + w] = sum_[m][qq];
                Qs[lrow * 8 + w] = sq_[m][qq];
            }
    __syncthreads();
    if (t < 64) {
        float ss = 0.f, qs = 0.f;
#pragma unroll
        for (int i = 0; i < 8; ++i) { ss += S[t * 8 + i]; qs += Qs[t * 8 + i]; }
        float mean = ss * (1.0f / E);
        float var = qs * (1.0f / E) - mean * mean;
        CB[t * 2] = mean;
        CB[t * 2 + 1] = rsqrtf(var + 1e-5f);
    }
    __syncthreads();

    float gf[8], bf_[8];
#pragma unroll
    for (int nf = 0; nf < 8; ++nf) {
        gf[nf] = fa.g[colbase + nf * 16];
        bf_[nf] = fa.b[colbase + nf * 16];
    }
#pragma unroll
    for (int m = 0; m < 4; ++m)
#pragma unroll
        for (int qq = 0; qq < 4; ++qq) {
            int lrow = m * 16 + kg * 4 + qq;
            float mean = CB[lrow * 2], rstd = CB[lrow * 2 + 1];
            float* op = fa.out + (size_t)(r0 + lrow) * E + colbase;
#pragma unroll
            for (int nf = 0; nf < 8; ++nf)
                op[nf * 16] = (acc[m][nf][qq] - mean) * rstd * gf[nf] + bf_[nf];
        }
}

extern "C" void kernel_launch(void* const* d_in, const int* in_sizes, int n_in,
                              void* d_out, int out_size, void* d_ws, size_t ws_size,
                              hipStream_t stream) {
    const float* user_emb = (const float*)d_in[0];
    const float* item_emb = (const float*)d_in[1];
    const float* u2i_in_w = (const float*)d_in[2];
    const float* u2i_in_b = (const float*)d_in[3];
    const float* u2i_out_w = (const float*)d_in[4];
    const float* u2i_out_b = (const float*)d_in[5];
    const float* i2u_in_w = (const float*)d_in[6];
    const float* i2u_in_b = (const float*)d_in[7];
    const float* i2u_out_w = (const float*)d_in[8];
    const float* i2u_out_b = (const float*)d_in[9];
    const float* user_g = (const float*)d_in[10];
    const float* user_b = (const float*)d_in[11];
    const float* item_g = (const float*)d_in[12];
    const float* item_b = (const float*)d_in[13];
    const float* alpha = (const float*)d_in[14];
    const float* beta = (const float*)d_in[15];

    float* out_u = (float*)d_out;
    float* out_i = out_u + (size_t)NB * E;

    // workspace: WvT 2x2MB bf16, M 2x1MB fp8, c 2x4KB
    short* WvT1 = (short*)d_ws;
    short* WvT2 = WvT1 + (size_t)E * E;
    unsigned char* M1 = (unsigned char*)(WvT2 + (size_t)E * E);
    unsigned char* M2 = M1 + (size_t)E * E;
    float* c1 = (float*)(M2 + (size_t)E * E);
    float* c2 = c1 + E;

    const dim3 b256(256);

    // 1) WvT = transpose(in_w[2E:3E]) in bf16
    wv_transpose<<<dim3(32, 32, 2), dim3(32, 8), 0, stream>>>(
        u2i_in_w + 2 * (size_t)E * E, WvT1, i2u_in_w + 2 * (size_t)E * E, WvT2);

    // 2) c = scale * (O @ bv + ob)   (alpha/beta folded into c only)
    bias_fuse<<<dim3(E, 1, 2), b256, 0, stream>>>(
        u2i_out_w, u2i_in_b + 2 * E, u2i_out_b, alpha, c1,
        i2u_out_w, i2u_in_b + 2 * E, i2u_out_b, beta, c2);

    // 3) M = 64 * (O @ Wv)   fp8 e4m3 [n][k]  (x64 keeps M in e4m3 normal range)
    gemm_m<<<dim3(8 * 8 * 2), b256, 0, stream>>>(
        GemmArgs{(const char*)u2i_out_w, WvT1, M1},
        GemmArgs{(const char*)i2u_out_w, WvT2, M2},
        8, 4096);

    // 4) fused GEMM(fp8, BK=64) + residual + LayerNorm (1024 blocks x 512 threads)
    fused_gemm_ln<<<dim3(1024), dim3(512), 0, stream>>>(
        FArgs{item_emb, M1, c1, user_emb, alpha, user_g, user_b, out_u},
        FArgs{user_emb, M2, c2, item_emb, beta, item_g, item_b, out_i});
}

// Round 18
// 304.971 us; speedup vs baseline: 1.4572x; 1.2007x over previous
//
#include <hip/hip_runtime.h>
#include <cstdint>
#include <cstddef>

#define E 1024
#define NB 32768
#define BM 128
#define BN 128

typedef __attribute__((ext_vector_type(4))) float f32x4;
typedef __attribute__((ext_vector_type(8))) short bf16x8;
typedef long long i64;

__device__ __forceinline__ short f2bfs(float x) {
    __bf16 h = (__bf16)x;
    return __builtin_bit_cast(short, h);
}
__device__ __forceinline__ bf16x8 cvt8(f32x4 lo, f32x4 hi) {
    bf16x8 r;
#pragma unroll
    for (int j = 0; j < 4; ++j) { r[j] = f2bfs(lo[j]); r[j + 4] = f2bfs(hi[j]); }
    return r;
}
// pack 4 f32 -> 4 fp8 e4m3 bytes (RNE)
__device__ __forceinline__ int pack4fp8(f32x4 v) {
    int r = __builtin_amdgcn_cvt_pk_fp8_f32(v[0], v[1], 0, false);
    r = __builtin_amdgcn_cvt_pk_fp8_f32(v[2], v[3], r, true);
    return r;
}
__device__ __forceinline__ unsigned char f2fp8(float x) {
    int r = __builtin_amdgcn_cvt_pk_fp8_f32(x, 0.f, 0, false);
    return (unsigned char)(r & 0xff);
}

__device__ __forceinline__ void gload16(const void* g, void* l) {
    __builtin_amdgcn_global_load_lds(
        (__attribute__((address_space(1))) void*)g,
        (__attribute__((address_space(3))) void*)l, 16, 0, 0);
}

// ---------------- transpose f32 -> bf16 (Wv -> WvT) ----------------
__global__ __launch_bounds__(256) void wv_transpose(const float* W0, short* T0,
                                                    const float* W1, short* T1) {
    const float* W = blockIdx.z ? W1 : W0;
    short* T = blockIdx.z ? T1 : T0;
    __shared__ float tile[32][33];
    const int j0 = blockIdx.x * 32, i0 = blockIdx.y * 32;
    const int tx = threadIdx.x, ty = threadIdx.y; // (32,8)
#pragma unroll
    for (int r = 0; r < 4; ++r)
        tile[ty + 8 * r][tx] = W[(size_t)(i0 + ty + 8 * r) * E + j0 + tx];
    __syncthreads();
#pragma unroll
    for (int r = 0; r < 4; ++r)
        T[(size_t)(j0 + ty + 8 * r) * E + i0 + tx] = f2bfs(tile[tx][ty + 8 * r]);
}

// ---------------- c[n] = scale * (sum_i O[n][i]*bv[i] + ob[n]) ----------------
__global__ __launch_bounds__(256) void bias_fuse(const float* O0, const float* bv0, const float* ob0, const float* s0, float* c0,
                                                 const float* O1, const float* bv1, const float* ob1, const float* s1, float* c1) {
    const float* O  = blockIdx.z ? O1 : O0;
    const float* bv = blockIdx.z ? bv1 : bv0;
    const float* ob = blockIdx.z ? ob1 : ob0;
    const float* sc = blockIdx.z ? s1 : s0;
    float* c = blockIdx.z ? c1 : c0;
    const int n = blockIdx.x, t = threadIdx.x;
    float s = 0.f;
    for (int i = t; i < E; i += 256) s += O[(size_t)n * E + i] * bv[i];
#pragma unroll
    for (int o = 32; o; o >>= 1) s += __shfl_down(s, o);
    __shared__ float rs[4];
    if ((t & 63) == 0) rs[t >> 6] = s;
    __syncthreads();
    if (t == 0) c[n] = sc[0] * (rs[0] + rs[1] + rs[2] + rs[3] + ob[n]);
}

// ---------------- M-build GEMM (R3-proven): M = 64*(O @ WvT^T), fp8 out ----------------
struct GemmArgs {
    const char* A;      // f32, row stride arstride
    const short* B;     // bf16 [n][k]
    unsigned char* C;   // fp8 e4m3 [n][k], row stride 1024 B, value x64
};

__global__ __launch_bounds__(256, 3) void gemm_m(GemmArgs g0, GemmArgs g1,
                                                 int mb, int arstride) {
    const int nwg = gridDim.x;
    const int q = nwg >> 3;
    const int wgid = (blockIdx.x & 7) * q + (blockIdx.x >> 3);
    const int per = mb * 8;
    const int z = wgid / per;
    const int rem = wgid - z * per;
    const int bx = rem >> 3;
    const int by = rem & 7;
    GemmArgs ga = z ? g1 : g0;

    constexpr int ABYTES = 16384;
    __shared__ __align__(16) char lds[2][ABYTES + 8192];

    const int t = threadIdx.x;
    const int l = t & 63, w = t >> 6;
    const int am0 = bx * BM, bn0 = by * BN;

    const char* gA[4];
#pragma unroll
    for (int i = 0; i < 4; ++i) {
        int c = i * 4 + w;
        int row = c * 8 + (l >> 3);
        int slot = (l & 7) ^ (row & 7);
        gA[i] = ga.A + (size_t)(am0 + row) * arstride + slot * 16;
    }
    const short* gB[2];
#pragma unroll
    for (int i = 0; i < 2; ++i) {
        int c = i * 4 + w;
        int row = c * 16 + (l >> 2);
        int slot = (l & 3) ^ ((row >> 1) & 3);
        gB[i] = ga.B + (size_t)(bn0 + row) * E + slot * 8;
    }

    auto stage = [&](int buf, int kt) {
#pragma unroll
        for (int i = 0; i < 4; ++i)
            gload16(gA[i] + (size_t)kt * 4, &lds[buf][(i * 4 + w) * 1024]);
#pragma unroll
        for (int i = 0; i < 2; ++i)
            gload16(gB[i] + kt, &lds[buf][ABYTES + (i * 4 + w) * 1024]);
    };

    const int wm = w >> 1, wn = w & 1;
    const int r16 = l & 15, kg = l >> 4;
    int aoff[4][2], boff[4];
#pragma unroll
    for (int m = 0; m < 4; ++m) {
        int row = wm * 64 + m * 16 + r16;
        aoff[m][0] = row * 128 + ((kg * 2) ^ (row & 7)) * 16;
        aoff[m][1] = row * 128 + ((kg * 2 + 1) ^ (row & 7)) * 16;
    }
#pragma unroll
    for (int n = 0; n < 4; ++n) {
        int row = wn * 64 + n * 16 + r16;
        boff[n] = ABYTES + row * 64 + (kg ^ ((row >> 1) & 3)) * 16;
    }

    f32x4 acc[4][4] = {};

    auto compute = [&](int buf) {
        bf16x8 a[4], b[4];
#pragma unroll
        for (int m = 0; m < 4; ++m) {
            f32x4 lo = *(const f32x4*)&lds[buf][aoff[m][0]];
            f32x4 hi = *(const f32x4*)&lds[buf][aoff[m][1]];
            a[m] = cvt8(lo, hi);
        }
#pragma unroll
        for (int n = 0; n < 4; ++n)
            b[n] = *(const bf16x8*)&lds[buf][boff[n]];
#pragma unroll
        for (int m = 0; m < 4; ++m)
#pragma unroll
            for (int n = 0; n < 4; ++n)
                acc[m][n] = __builtin_amdgcn_mfma_f32_16x16x32_bf16(a[m], b[n], acc[m][n], 0, 0, 0);
    };

    stage(0, 0);
    __syncthreads();
#pragma unroll 1
    for (int kt = 0; kt < E; kt += 64) {
        stage(1, kt + 32);
        compute(0);
        __syncthreads();
        if (kt + 64 < E) stage(0, kt + 64);
        compute(1);
        __syncthreads();
    }

    const int ccol0 = bn0 + wn * 64 + r16;
    const int crow0 = am0 + wm * 64 + kg * 4;
#pragma unroll
    for (int m = 0; m < 4; ++m)
#pragma unroll
        for (int n = 0; n < 4; ++n)
#pragma unroll
            for (int qq = 0; qq < 4; ++qq) {
                int row = crow0 + m * 16 + qq;
                int col = ccol0 + n * 16;
                ga.C[(size_t)row * 1024 + col] = f2fp8(acc[m][n][qq] * 64.0f);
            }
}

// ============ fused: out = LN(q + (kv @ M^T)*alpha/64 + c) * g + b ============
// R15 VERBATIM (session best: 289us fused / 305us total). Structure: 64-row
// full-width tile, BK=32, 2-barrier dbuf, fp8 operands, conflict-fixed
// (row>>2)&1 bank hash, per-block K-phase rotation (L2 de-hotspot), XCD
// pair-scheduling. Mapped-and-rejected: 2 blk/CU (R14/R16 -140us), BK=64
// (R17 -65us), counted-vmcnt (R7/R8 -30us), split GEMM+LN (R10 -95us).
struct FArgs {
    const float* kv;        // [32768][1024] f32  (GEMM A)
    const unsigned char* M; // [1024][1024] fp8 e4m3 [n][k], value x64, NO alpha
    const float* c;         // [1024] f32, alpha folded
    const float* q;         // [32768][1024] f32  (residual emb)
    const float* scale;     // alpha (1 elem)
    const float* g;
    const float* b;
    float* out;             // [32768][1024] f32
};

#define BBASE 4096

__global__ __launch_bounds__(512, 2) void fused_gemm_ln(FArgs f0, FArgs f1) {
    // pair-scheduling swizzle: consecutive slots on one XCD alternate tables at
    // the SAME mb, so the pair shares emb panels (kv of one = residual of other).
    const int bid = blockIdx.x;
    const int u = bid >> 3, xcd = bid & 7;
    const int z = u & 1;
    const int mb = xcd * 64 + (u >> 1);
    const FArgs fa = z ? f1 : f0;
    const int r0 = mb * 64;
    const int off = u & 31;                 // K-phase rotation (L2 de-hotspot)

    __shared__ __align__(16) char lds[69632];

    const int t = threadIdx.x;
    const int l = t & 63, w = t >> 6;
    const int r16 = l & 15, kg = l >> 4;

    // ---- B staging map: 32KB/buf = 2048 16B-units; gi=c*512+t; row=gi>>1, s=gi&1
    //      inverse 16B swizzle on source: s ^= (row>>2)&1 ----
    int bsrc[4];
#pragma unroll
    for (int c = 0; c < 4; ++c) {
        int gi = c * 512 + t;
        int row = gi >> 1, s = gi & 1;
        bsrc[c] = row * 1024 + ((s ^ ((row >> 2) & 1)) * 16);
    }
    auto stageB = [&](int buf, int kt) {   // kt = k index = byte offset in fp8 row
#pragma unroll
        for (int c = 0; c < 4; ++c)
            gload16(fa.M + bsrc[c] + kt,
                    &lds[BBASE + buf * 32768 + (c * 512 + t) * 16]);
    };

    // ---- A commit map: thread -> row t>>3 (64 rows), 4-float quad kp=t&7 ----
    const int ar = t >> 3, kp = t & 7;
    const float* Ag = fa.kv + (size_t)(r0 + ar) * E + kp * 4;
    const int awoff = ar * 32 + (((kp >> 2) ^ ((ar >> 2) & 1)) * 16) + (kp & 3) * 4;
    auto commitA = [&](int buf, f32x4 av) {
        *(int*)&lds[buf * 2048 + awoff] = pack4fp8(av);
    };

    // ---- read-side swizzled frag offsets (8B frags, 16B-granular swizzle) ----
    int aoff[4], boff[8];
    const int kgh = kg >> 1, kglo = (kg & 1) * 8;
#pragma unroll
    for (int m = 0; m < 4; ++m) {
        int row = m * 16 + r16;
        aoff[m] = row * 32 + ((kgh ^ ((row >> 2) & 1)) * 16) + kglo;
    }
#pragma unroll
    for (int nf = 0; nf < 8; ++nf) {
        int row = w * 128 + nf * 16 + r16;
        boff[nf] = BBASE + row * 32 + ((kgh ^ ((row >> 2) & 1)) * 16) + kglo;
    }

    f32x4 acc[4][8] = {};

    auto compute = [&](int buf) {
        i64 a[4], b[8];
#pragma unroll
        for (int m = 0; m < 4; ++m)
            a[m] = *(const i64*)&lds[buf * 2048 + aoff[m]];
#pragma unroll
        for (int nf = 0; nf < 8; ++nf)
            b[nf] = *(const i64*)&lds[buf * 32768 + boff[nf]];
#pragma unroll
        for (int m = 0; m < 4; ++m)
#pragma unroll
            for (int nf = 0; nf < 8; ++nf)
                acc[m][nf] = __builtin_amdgcn_mfma_f32_16x16x32_fp8_fp8(a[m], b[nf], acc[m][nf], 0, 0, 0);
    };

    // rotated k for phase p
    auto K = [&](int p) { return ((p + off) & 31) << 5; };

    // ---- prologue (R13 pattern, rotated): buf0 staged with K(0); reg holds K(1) ----
    {
        f32x4 a0 = *(const f32x4*)(Ag + K(0));
        stageB(0, K(0));
        commitA(0, a0);
    }
    f32x4 a = *(const f32x4*)(Ag + K(1));
    __syncthreads();

#pragma unroll 1
    for (int p = 0; p < 32; p += 2) {
        const bool has2 = (p + 2) < 32;
        stageB(1, K(p + 1));
        compute(0);                           // B/A at K(p), buf0
        commitA(1, a);                        // A at K(p+1)
        if (has2) a = *(const f32x4*)(Ag + K(p + 2));
        __syncthreads();                      // buf1 staged+committed
        if (has2) stageB(0, K(p + 2));
        compute(1);                           // B/A at K(p+1), buf1
        if (has2) {
            commitA(0, a);                    // A at K(p+2)
            if (p + 3 < 32) a = *(const f32x4*)(Ag + K(p + 3));
        }
        __syncthreads();
    }
    __syncthreads();   // LDS free for LN scratch

    // ---- epilogue: residual + LayerNorm ----
    float* S  = (float*)lds;            // [64][8] row sums
    float* Qs = (float*)(lds + 2048);   // [64][8] row sumsq
    float* CB = (float*)(lds + 4096);   // [64][2] mean,rstd

    const float sc = fa.scale[0] * (1.0f / 64.0f);
    const int colbase = w * 128 + r16;
    float cf[8];
#pragma unroll
    for (int nf = 0; nf < 8; ++nf) cf[nf] = fa.c[colbase + nf * 16];

    float sum_[4][4] = {}, sq_[4][4] = {};
#pragma unroll
    for (int m = 0; m < 4; ++m) {
#pragma unroll
        for (int nf = 0; nf < 8; ++nf) {
#pragma unroll
            for (int qq = 0; qq < 4; ++qq) {
                int lrow = m * 16 + kg * 4 + qq;
                float x = acc[m][nf][qq] * sc + cf[nf]
                        + fa.q[(size_t)(r0 + lrow) * E + colbase + nf * 16];
                acc[m][nf][qq] = x;
                sum_[m][qq] += x;
                sq_[m][qq] += x * x;
            }
        }
    }
#pragma unroll
    for (int m = 0; m < 4; ++m)
#pragma unroll
        for (int qq = 0; qq < 4; ++qq)
#pragma unroll
            for (int o = 1; o < 16; o <<= 1) {
                sum_[m][qq] += __shfl_xor(sum_[m][qq], o);
                sq_[m][qq] += __shfl_xor(sq_[m][qq], o);
            }
#pragma unroll
    for (int m = 0; m < 4; ++m)
#pragma unroll
        for (int qq = 0; qq < 4; ++qq)
            if (r16 == m * 4 + qq) {
                int lrow = m * 16 + kg * 4 + qq;
                S[lrow * 8 + w] = sum_[m][qq];
                Qs[lrow * 8 + w] = sq_[m][qq];
            }
    __syncthreads();
    if (t < 64) {
        float ss = 0.f, qs = 0.f;
#pragma unroll
        for (int i = 0; i < 8; ++i) { ss += S[t * 8 + i]; qs += Qs[t * 8 + i]; }
        float mean = ss * (1.0f / E);
        float var = qs * (1.0f / E) - mean * mean;
        CB[t * 2] = mean;
        CB[t * 2 + 1] = rsqrtf(var + 1e-5f);
    }
    __syncthreads();

    float gf[8], bf_[8];
#pragma unroll
    for (int nf = 0; nf < 8; ++nf) {
        gf[nf] = fa.g[colbase + nf * 16];
        bf_[nf] = fa.b[colbase + nf * 16];
    }
#pragma unroll
    for (int m = 0; m < 4; ++m)
#pragma unroll
        for (int qq = 0; qq < 4; ++qq) {
            int lrow = m * 16 + kg * 4 + qq;
            float mean = CB[lrow * 2], rstd = CB[lrow * 2 + 1];
            float* op = fa.out + (size_t)(r0 + lrow) * E + colbase;
#pragma unroll
            for (int nf = 0; nf < 8; ++nf)
                op[nf * 16] = (acc[m][nf][qq] - mean) * rstd * gf[nf] + bf_[nf];
        }
}

extern "C" void kernel_launch(void* const* d_in, const int* in_sizes, int n_in,
                              void* d_out, int out_size, void* d_ws, size_t ws_size,
                              hipStream_t stream) {
    const float* user_emb = (const float*)d_in[0];
    const float* item_emb = (const float*)d_in[1];
    const float* u2i_in_w = (const float*)d_in[2];
    const float* u2i_in_b = (const float*)d_in[3];
    const float* u2i_out_w = (const float*)d_in[4];
    const float* u2i_out_b = (const float*)d_in[5];
    const float* i2u_in_w = (const float*)d_in[6];
    const float* i2u_in_b = (const float*)d_in[7];
    const float* i2u_out_w = (const float*)d_in[8];
    const float* i2u_out_b = (const float*)d_in[9];
    const float* user_g = (const float*)d_in[10];
    const float* user_b = (const float*)d_in[11];
    const float* item_g = (const float*)d_in[12];
    const float* item_b = (const float*)d_in[13];
    const float* alpha = (const float*)d_in[14];
    const float* beta = (const float*)d_in[15];

    float* out_u = (float*)d_out;
    float* out_i = out_u + (size_t)NB * E;

    // workspace: WvT 2x2MB bf16, M 2x1MB fp8, c 2x4KB
    short* WvT1 = (short*)d_ws;
    short* WvT2 = WvT1 + (size_t)E * E;
    unsigned char* M1 = (unsigned char*)(WvT2 + (size_t)E * E);
    unsigned char* M2 = M1 + (size_t)E * E;
    float* c1 = (float*)(M2 + (size_t)E * E);
    float* c2 = c1 + E;

    const dim3 b256(256);

    // 1) WvT = transpose(in_w[2E:3E]) in bf16
    wv_transpose<<<dim3(32, 32, 2), dim3(32, 8), 0, stream>>>(
        u2i_in_w + 2 * (size_t)E * E, WvT1, i2u_in_w + 2 * (size_t)E * E, WvT2);

    // 2) c = scale * (O @ bv + ob)   (alpha/beta folded into c only)
    bias_fuse<<<dim3(E, 1, 2), b256, 0, stream>>>(
        u2i_out_w, u2i_in_b + 2 * E, u2i_out_b, alpha, c1,
        i2u_out_w, i2u_in_b + 2 * E, i2u_out_b, beta, c2);

    // 3) M = 64 * (O @ Wv)   fp8 e4m3 [n][k]  (x64 keeps M in e4m3 normal range)
    gemm_m<<<dim3(8 * 8 * 2), b256, 0, stream>>>(
        GemmArgs{(const char*)u2i_out_w, WvT1, M1},
        GemmArgs{(const char*)i2u_out_w, WvT2, M2},
        8, 4096);

    // 4) fused GEMM(fp8) + residual + LayerNorm (1024 blocks x 512 threads)
    fused_gemm_ln<<<dim3(1024), dim3(512), 0, stream>>>(
        FArgs{item_emb, M1, c1, user_emb, alpha, user_g, user_b, out_u},
        FArgs{user_emb, M2, c2, item_emb, beta, item_g, item_b, out_i});
}